// Round 4
// baseline (493.483 us; speedup 1.0000x reference)
//
#include <hip/hip_runtime.h>

#define HW 4096
#define CCH 256
#define IC 128

typedef __bf16 bf16x8 __attribute__((ext_vector_type(8)));
typedef float f32x4 __attribute__((ext_vector_type(4)));

#define MFMA16(a, b, c) __builtin_amdgcn_mfma_f32_16x16x32_bf16(a, b, c, 0, 0, 0)

static __device__ __forceinline__ float4 ld4(const float* p) {
  return *reinterpret_cast<const float4*>(p);
}
static __device__ __forceinline__ void st4(float* p, float4 v) {
  *reinterpret_cast<float4*>(p) = v;
}
static __device__ __forceinline__ unsigned int pack_bf16(float a, float b) {
  union { __bf16 h; unsigned short u; } ua, ub;
  ua.h = (__bf16)a; ub.h = (__bf16)b;
  return ((unsigned int)ub.u << 16) | (unsigned int)ua.u;
}
static __device__ __forceinline__ bf16x8 ldb8(const __bf16* p) {
  return *reinterpret_cast<const bf16x8*>(p);
}

// ---------------------------------------------------------------------------
// theta projection (pixel-major bf16) + xB emission (x transposed, bf16 [px][256])
__global__ __launch_bounds__(256) void k_projT(const float* __restrict__ in,
                                               const float* __restrict__ w,
                                               const float* __restrict__ bias,
                                               __bf16* __restrict__ out,
                                               __bf16* __restrict__ xB) {
  const int n = blockIdx.y;
  const int p0 = blockIdx.x * 64;
  const float* inN = in + (size_t)n * CCH * HW;
  __shared__ float sIn[16][68];
  __shared__ float sW[16][132];
  const int tid = threadIdx.x;
  const int tp = tid & 15, to = tid >> 4;
  const int px = tid & 63, cp = tid >> 6;
  float acc[4][8];
#pragma unroll
  for (int i = 0; i < 4; ++i)
#pragma unroll
    for (int j = 0; j < 8; ++j) acc[i][j] = 0.f;

  for (int c0 = 0; c0 < CCH; c0 += 16) {
    __syncthreads();
    {
      int cc = tid >> 4, p4 = tid & 15;
      st4(&sIn[cc][p4 * 4], ld4(&inN[(size_t)(c0 + cc) * HW + p0 + p4 * 4]));
    }
#pragma unroll
    for (int i = 0; i < 2; ++i) {
      int e4 = tid + 256 * i;
      int o = e4 >> 2, c4 = e4 & 3;
      float4 wv = ld4(&w[(size_t)o * CCH + c0 + c4 * 4]);
      sW[c4 * 4 + 0][o] = wv.x;
      sW[c4 * 4 + 1][o] = wv.y;
      sW[c4 * 4 + 2][o] = wv.z;
      sW[c4 * 4 + 3][o] = wv.w;
    }
    __syncthreads();
    {
      unsigned int* xr = (unsigned int*)(xB + ((size_t)n * HW + p0 + px) * 256 + c0);
#pragma unroll
      for (int i = 0; i < 2; ++i) {
        int ch2 = 2 * (cp + 4 * i);
        xr[cp + 4 * i] = pack_bf16(sIn[ch2][px], sIn[ch2 + 1][px]);
      }
    }
#pragma unroll
    for (int kk = 0; kk < 16; ++kk) {
      float4 bv = ld4(&sIn[kk][tp * 4]);
      float4 a0 = ld4(&sW[kk][to * 8]);
      float4 a1 = ld4(&sW[kk][to * 8 + 4]);
      float bb[4] = {bv.x, bv.y, bv.z, bv.w};
      float aa[8] = {a0.x, a0.y, a0.z, a0.w, a1.x, a1.y, a1.z, a1.w};
#pragma unroll
      for (int i = 0; i < 4; ++i)
#pragma unroll
        for (int j = 0; j < 8; ++j) acc[i][j] = fmaf(bb[i], aa[j], acc[i][j]);
    }
  }
  float bs[8];
#pragma unroll
  for (int j = 0; j < 8; ++j) bs[j] = bias[to * 8 + j];
  __bf16* dst = out + ((size_t)n * HW + p0) * IC;
#pragma unroll
  for (int i = 0; i < 4; ++i) {
    bf16x8 v;
#pragma unroll
    for (int j = 0; j < 8; ++j) v[j] = (__bf16)(acc[i][j] + bs[j]);
    *reinterpret_cast<bf16x8*>(&dst[(size_t)(tp * 4 + i) * IC + to * 8]) = v;
  }
}

// ---------------------------------------------------------------------------
// phi (pixel-major) + g (channel-major) projections, one pass over x_ref
__global__ __launch_bounds__(256) void k_projPG(const float* __restrict__ in,
                                                const float* __restrict__ wPhi,
                                                const float* __restrict__ wG,
                                                const float* __restrict__ bPhi,
                                                const float* __restrict__ bG,
                                                __bf16* __restrict__ phB,
                                                __bf16* __restrict__ gB) {
  const int n = blockIdx.y;
  const int p0 = blockIdx.x * 64;
  const float* inN = in + (size_t)n * CCH * HW;
  __shared__ float sIn[16][68];
  __shared__ float sW[16][264];
  __shared__ __attribute__((aligned(16))) __bf16 sT[128][72];
  const int tid = threadIdx.x;
  const int tp = tid & 15, to = tid >> 4;
  float acc[4][16];
#pragma unroll
  for (int i = 0; i < 4; ++i)
#pragma unroll
    for (int j = 0; j < 16; ++j) acc[i][j] = 0.f;

  for (int c0 = 0; c0 < CCH; c0 += 16) {
    __syncthreads();
    {
      int cc = tid >> 4, p4 = tid & 15;
      st4(&sIn[cc][p4 * 4], ld4(&inN[(size_t)(c0 + cc) * HW + p0 + p4 * 4]));
    }
#pragma unroll
    for (int i = 0; i < 4; ++i) {
      int e4 = tid + 256 * i;
      int o = e4 >> 2, c4 = e4 & 3;
      const float* wsrc = (o < 128) ? &wPhi[(size_t)o * CCH + c0 + c4 * 4]
                                    : &wG[(size_t)(o - 128) * CCH + c0 + c4 * 4];
      float4 wv = ld4(wsrc);
      sW[c4 * 4 + 0][o] = wv.x;
      sW[c4 * 4 + 1][o] = wv.y;
      sW[c4 * 4 + 2][o] = wv.z;
      sW[c4 * 4 + 3][o] = wv.w;
    }
    __syncthreads();
#pragma unroll
    for (int kk = 0; kk < 16; ++kk) {
      float4 bv = ld4(&sIn[kk][tp * 4]);
      float bb[4] = {bv.x, bv.y, bv.z, bv.w};
      float aa[16];
      float4 a0 = ld4(&sW[kk][to * 16 + 0]);
      float4 a1 = ld4(&sW[kk][to * 16 + 4]);
      float4 a2 = ld4(&sW[kk][to * 16 + 8]);
      float4 a3 = ld4(&sW[kk][to * 16 + 12]);
      aa[0]=a0.x; aa[1]=a0.y; aa[2]=a0.z; aa[3]=a0.w;
      aa[4]=a1.x; aa[5]=a1.y; aa[6]=a1.z; aa[7]=a1.w;
      aa[8]=a2.x; aa[9]=a2.y; aa[10]=a2.z; aa[11]=a2.w;
      aa[12]=a3.x; aa[13]=a3.y; aa[14]=a3.z; aa[15]=a3.w;
#pragma unroll
      for (int i = 0; i < 4; ++i)
#pragma unroll
        for (int j = 0; j < 16; ++j) acc[i][j] = fmaf(bb[i], aa[j], acc[i][j]);
    }
  }
  float bs[16];
#pragma unroll
  for (int j = 0; j < 16; ++j) {
    int o = to * 16 + j;
    bs[j] = (o < 128) ? bPhi[o] : bG[o - 128];
  }
  if (to < 8) {
    __bf16* dst = phB + ((size_t)n * HW + p0) * IC;
#pragma unroll
    for (int i = 0; i < 4; ++i) {
      bf16x8 v0, v1;
#pragma unroll
      for (int j = 0; j < 8; ++j) {
        v0[j] = (__bf16)(acc[i][j] + bs[j]);
        v1[j] = (__bf16)(acc[i][8 + j] + bs[8 + j]);
      }
      *reinterpret_cast<bf16x8*>(&dst[(size_t)(tp * 4 + i) * IC + to * 16]) = v0;
      *reinterpret_cast<bf16x8*>(&dst[(size_t)(tp * 4 + i) * IC + to * 16 + 8]) = v1;
    }
  }
  __syncthreads();
  if (to >= 8) {
#pragma unroll
    for (int i = 0; i < 4; ++i)
#pragma unroll
      for (int j = 0; j < 16; ++j)
        sT[(to - 8) * 16 + j][tp * 4 + i] = (__bf16)(acc[i][j] + bs[j]);
  }
  __syncthreads();
  const int row = tid >> 1, half = tid & 1;
  __bf16* dst = gB + (size_t)n * IC * HW + (size_t)row * HW + p0 + half * 32;
#pragma unroll
  for (int m = 0; m < 4; ++m)
    *reinterpret_cast<bf16x8*>(&dst[m * 8]) =
        *reinterpret_cast<const bf16x8*>(&sT[row][half * 32 + m * 8]);
}

// ---------------------------------------------------------------------------
// prep: W2 = c1y@out_w (bf16), bias2 = c1_b + c1y@out_b, cast c1x & out_w to bf16
__global__ __launch_bounds__(256) void k_prep(const float* __restrict__ c1_w,
                                              const float* __restrict__ c1_b,
                                              const float* __restrict__ out_w,
                                              const float* __restrict__ out_b,
                                              __bf16* __restrict__ c1xB,
                                              __bf16* __restrict__ W2B,
                                              __bf16* __restrict__ outwB,
                                              float* __restrict__ bias2) {
  const int bx = blockIdx.x, tid = threadIdx.x;
  if (bx < 256) {
    const int o = bx;
    c1xB[(size_t)o * 256 + tid] = (__bf16)c1_w[(size_t)o * 512 + tid];
    if (tid < 128) {
      float s = 0.f;
      for (int c = 0; c < 256; ++c)
        s = fmaf(c1_w[(size_t)o * 512 + 256 + c], out_w[(size_t)c * 128 + tid], s);
      W2B[(size_t)o * 128 + tid] = (__bf16)s;
    } else if (tid == 128) {
      float s = 0.f;
      for (int c = 0; c < 256; ++c)
        s = fmaf(c1_w[(size_t)o * 512 + 256 + c], out_b[c], s);
      bias2[o] = c1_b[o] + s;
    }
  } else {
    const int o = bx - 256;
    if (tid < 128) outwB[(size_t)o * 128 + tid] = (__bf16)out_w[(size_t)o * 128 + tid];
  }
}

// ---------------------------------------------------------------------------
// Single-pass fused attention: E (bf16 tiled) + rowsum inv + y (=E@g * inv)
// + fused out-conv epilogue (y2b). grid (64,4), 512 thr = 8 waves (qg, kh)
__global__ __launch_bounds__(512) void k_attn2(const __bf16* __restrict__ thB,
                                               const __bf16* __restrict__ phB,
                                               const __bf16* __restrict__ gB,
                                               const __bf16* __restrict__ outwB,
                                               const float* __restrict__ outb,
                                               __bf16* __restrict__ Ews,
                                               float* __restrict__ invW,
                                               __bf16* __restrict__ yTB,
                                               __bf16* __restrict__ y2b) {
  const int n = blockIdx.y;
  const int qb = blockIdx.x;
  const int q0 = qb * 64;
  const int tid = threadIdx.x;
  const int wv = tid >> 6;
  const int lane = tid & 63;
  const int qg = wv & 3;
  const int kh = wv >> 2;
  const int l15 = lane & 15;
  const int lg = lane >> 4;

  __shared__ __attribute__((aligned(16))) __bf16 sPhi[2][64][136];
  __shared__ __attribute__((aligned(16))) __bf16 sG[2][128][72];
  __shared__ __attribute__((aligned(16))) __bf16 sPb[8][16][72];
  __shared__ float sY[64][132];
  __shared__ float sRS[2][64];
  __shared__ float sInv[64];

  const __bf16* phN = phB + (size_t)n * HW * IC;
  const __bf16* gN = gB + (size_t)n * IC * HW;
  const float scale = 0.08838834764831845f;  // 1/sqrt(128)

  const __bf16* thRow = thB + ((size_t)n * HW + q0 + qg * 16 + l15) * IC + lg * 8;
  bf16x8 aQ[4];
#pragma unroll
  for (int cj = 0; cj < 4; ++cj) aQ[cj] = ldb8(thRow + 32 * cj);

  const int u = tid & 255;
  float rs[4] = {0.f, 0.f, 0.f, 0.f};
  f32x4 accY[8];
#pragma unroll
  for (int t = 0; t < 8; ++t) accY[t] = (f32x4){0, 0, 0, 0};

  __bf16* Eblk = Ews + ((size_t)(n * 64 + qb) * 32) * 8192 + wv * 1024 + lane * 16;

  for (int it = 0; it < 32; ++it) {
    const int k0 = kh * 2048 + it * 64;
    __syncthreads();
#pragma unroll
    for (int rep = 0; rep < 4; ++rep) {
      int row = (u >> 4) + rep * 16, seg = u & 15;
      *reinterpret_cast<bf16x8*>(&sPhi[kh][row][seg * 8]) =
          ldb8(&phN[(size_t)(k0 + row) * IC + seg * 8]);
    }
#pragma unroll
    for (int rep = 0; rep < 4; ++rep) {
      int row = (u >> 3) + rep * 32, seg = u & 7;
      *reinterpret_cast<bf16x8*>(&sG[kh][row][seg * 8]) =
          ldb8(&gN[(size_t)row * HW + k0 + seg * 8]);
    }
    __syncthreads();
    f32x4 cc[4] = {{0, 0, 0, 0}, {0, 0, 0, 0}, {0, 0, 0, 0}, {0, 0, 0, 0}};
#pragma unroll
    for (int kt = 0; kt < 4; ++kt)
#pragma unroll
      for (int cj = 0; cj < 4; ++cj) {
        bf16x8 b = ldb8(&sPhi[kh][kt * 16 + l15][cj * 32 + lg * 8]);
        cc[kt] = MFMA16(aQ[cj], b, cc[kt]);
      }
#pragma unroll
    for (int kt = 0; kt < 4; ++kt)
#pragma unroll
      for (int r = 0; r < 4; ++r) {
        float e = __expf(cc[kt][r] * scale);
        rs[r] += e;
        sPb[wv][lg * 4 + r][kt * 16 + l15] = (__bf16)e;
      }
    // PV with unnormalized E (sPb is wave-private: no barrier needed)
    bf16x8 aP0 = ldb8(&sPb[wv][l15][lg * 8]);
    bf16x8 aP1 = ldb8(&sPb[wv][l15][lg * 8 + 32]);
#pragma unroll
    for (int t = 0; t < 8; ++t) {
      bf16x8 b0 = ldb8(&sG[kh][t * 16 + l15][lg * 8]);
      bf16x8 b1 = ldb8(&sG[kh][t * 16 + l15][lg * 8 + 32]);
      accY[t] = MFMA16(aP0, b0, accY[t]);
      accY[t] = MFMA16(aP1, b1, accY[t]);
    }
    // coalesced E tile store (1 KB contiguous per wave)
    {
      const int rr = lane >> 2, cs = (lane & 3) * 16;
      bf16x8 e0 = ldb8(&sPb[wv][rr][cs]);
      bf16x8 e1 = ldb8(&sPb[wv][rr][cs + 8]);
      __bf16* ep = Eblk + (size_t)it * 8192;
      *reinterpret_cast<bf16x8*>(ep) = e0;
      *reinterpret_cast<bf16x8*>(ep + 8) = e1;
    }
  }

#pragma unroll
  for (int m = 1; m < 16; m <<= 1)
#pragma unroll
    for (int r = 0; r < 4; ++r) rs[r] += __shfl_xor(rs[r], m, 64);
  if (l15 == 0) {
#pragma unroll
    for (int r = 0; r < 4; ++r) sRS[kh][qg * 16 + lg * 4 + r] = rs[r];
  }
  __syncthreads();
  if (tid < 64) {
    float iv = 1.f / (sRS[0][tid] + sRS[1][tid]);
    sInv[tid] = iv;
    invW[(size_t)n * HW + q0 + tid] = iv;
  }
  __syncthreads();
  float inv4[4];
#pragma unroll
  for (int r = 0; r < 4; ++r) inv4[r] = sInv[qg * 16 + lg * 4 + r];

  if (kh == 0) {
#pragma unroll
    for (int t = 0; t < 8; ++t)
#pragma unroll
      for (int r = 0; r < 4; ++r)
        sY[qg * 16 + lg * 4 + r][t * 16 + l15] = accY[t][r];
  }
  __syncthreads();
  if (kh == 1) {
    __bf16* yRow = yTB + ((size_t)n * HW + q0 + qg * 16) * IC;
#pragma unroll
    for (int t = 0; t < 8; ++t)
#pragma unroll
      for (int r = 0; r < 4; ++r) {
        float v = (accY[t][r] + sY[qg * 16 + lg * 4 + r][t * 16 + l15]) * inv4[r];
        sY[qg * 16 + lg * 4 + r][t * 16 + l15] = v;
        yRow[(size_t)(lg * 4 + r) * IC + t * 16 + l15] = (__bf16)v;
      }
  }
  __syncthreads();

  // fused out-conv: y2 = out_w @ y + out_b ; each wave does 32 o x 64 px
  const int o0 = wv * 32;
  f32x4 acc2[2][4];
#pragma unroll
  for (int i = 0; i < 2; ++i)
#pragma unroll
    for (int j = 0; j < 4; ++j) acc2[i][j] = (f32x4){0, 0, 0, 0};
#pragma unroll
  for (int s = 0; s < 4; ++s) {
    bf16x8 a2[2], b2[4];
#pragma unroll
    for (int i = 0; i < 2; ++i)
      a2[i] = ldb8(&outwB[(size_t)(o0 + i * 16 + l15) * 128 + s * 32 + lg * 8]);
#pragma unroll
    for (int j = 0; j < 4; ++j) {
      float4 f0 = ld4(&sY[j * 16 + l15][s * 32 + lg * 8]);
      float4 f1 = ld4(&sY[j * 16 + l15][s * 32 + lg * 8 + 4]);
      bf16x8 bv;
      bv[0] = (__bf16)f0.x; bv[1] = (__bf16)f0.y; bv[2] = (__bf16)f0.z; bv[3] = (__bf16)f0.w;
      bv[4] = (__bf16)f1.x; bv[5] = (__bf16)f1.y; bv[6] = (__bf16)f1.z; bv[7] = (__bf16)f1.w;
      b2[j] = bv;
    }
#pragma unroll
    for (int i = 0; i < 2; ++i)
#pragma unroll
      for (int j = 0; j < 4; ++j) acc2[i][j] = MFMA16(a2[i], b2[j], acc2[i][j]);
  }
#pragma unroll
  for (int i = 0; i < 2; ++i)
#pragma unroll
    for (int r = 0; r < 4; ++r) {
      int o = o0 + i * 16 + lg * 4 + r;
      float bb = outb[o];
      __bf16* dst = y2b + ((size_t)n * CCH + o) * HW + q0;
#pragma unroll
      for (int j = 0; j < 4; ++j)
        dst[j * 16 + l15] = (__bf16)(acc2[i][j][r] + bb);
    }
}

// ---------------------------------------------------------------------------
// normalize: P[n][q][k] = fp32(E_tiled) * inv[q] — pure streaming
__global__ __launch_bounds__(512) void k_norm(const __bf16* __restrict__ Ews,
                                              const float* __restrict__ invW,
                                              float* __restrict__ P) {
  const int n = blockIdx.y;
  const int qb = blockIdx.x;
  const int tid = threadIdx.x;
  __shared__ float sInv[64];
  if (tid < 64) sInv[tid] = invW[(size_t)n * HW + qb * 64 + tid];
  __syncthreads();
  const int wv = tid >> 6;
  const int qg = wv & 3, kh = wv >> 2;
  const int row = (tid >> 2) & 15, cq = tid & 3;
  const int q = qb * 64 + qg * 16 + row;
  const float iv = sInv[qg * 16 + row];
  const __bf16* eb = Ews + ((size_t)(n * 64 + qb) * 32) * 8192 + tid * 16;
  float* prow = P + ((size_t)n * HW + q) * HW + kh * 2048 + cq * 16;
  for (int it = 0; it < 32; ++it) {
    bf16x8 v0 = ldb8(eb + (size_t)it * 8192);
    bf16x8 v1 = ldb8(eb + (size_t)it * 8192 + 8);
    float* pw = prow + it * 64;
    st4(pw + 0, make_float4((float)v0[0] * iv, (float)v0[1] * iv, (float)v0[2] * iv, (float)v0[3] * iv));
    st4(pw + 4, make_float4((float)v0[4] * iv, (float)v0[5] * iv, (float)v0[6] * iv, (float)v0[7] * iv));
    st4(pw + 8, make_float4((float)v1[0] * iv, (float)v1[1] * iv, (float)v1[2] * iv, (float)v1[3] * iv));
    st4(pw + 12, make_float4((float)v1[4] * iv, (float)v1[5] * iv, (float)v1[6] * iv, (float)v1[7] * iv));
  }
}

// ---------------------------------------------------------------------------
// c1 via MFMA (LDS-free): coef1 = relu(c1xB@xB + W2B@yTB + bias2), bf16 out
__global__ __launch_bounds__(256) void k_c1m(const __bf16* __restrict__ xB,
                                             const __bf16* __restrict__ yTB,
                                             const __bf16* __restrict__ c1xB,
                                             const __bf16* __restrict__ W2B,
                                             const float* __restrict__ bias2,
                                             __bf16* __restrict__ coef1) {
  const int n = blockIdx.y;
  const int px0 = blockIdx.x * 64;
  const int tid = threadIdx.x;
  const int w = tid >> 6, lane = tid & 63;
  const int l15 = lane & 15, lg = lane >> 4;
  const int o0 = w * 64;
  f32x4 acc[4][4];
#pragma unroll
  for (int i = 0; i < 4; ++i)
#pragma unroll
    for (int j = 0; j < 4; ++j) acc[i][j] = (f32x4){0, 0, 0, 0};

  const __bf16* xRow = xB + ((size_t)n * HW + px0) * 256;
  const __bf16* yRow = yTB + ((size_t)n * HW + px0) * 128;

#pragma unroll
  for (int s = 0; s < 8; ++s) {
    bf16x8 a[4], b[4];
#pragma unroll
    for (int t = 0; t < 4; ++t) {
      a[t] = ldb8(&c1xB[(size_t)(o0 + t * 16 + l15) * 256 + s * 32 + lg * 8]);
      b[t] = ldb8(&xRow[(size_t)(t * 16 + l15) * 256 + s * 32 + lg * 8]);
    }
#pragma unroll
    for (int i = 0; i < 4; ++i)
#pragma unroll
      for (int j = 0; j < 4; ++j) acc[i][j] = MFMA16(a[i], b[j], acc[i][j]);
  }
#pragma unroll
  for (int s = 0; s < 4; ++s) {
    bf16x8 a[4], b[4];
#pragma unroll
    for (int t = 0; t < 4; ++t) {
      a[t] = ldb8(&W2B[(size_t)(o0 + t * 16 + l15) * 128 + s * 32 + lg * 8]);
      b[t] = ldb8(&yRow[(size_t)(t * 16 + l15) * 128 + s * 32 + lg * 8]);
    }
#pragma unroll
    for (int i = 0; i < 4; ++i)
#pragma unroll
      for (int j = 0; j < 4; ++j) acc[i][j] = MFMA16(a[i], b[j], acc[i][j]);
  }
#pragma unroll
  for (int i = 0; i < 4; ++i)
#pragma unroll
    for (int r = 0; r < 4; ++r) {
      int o = o0 + i * 16 + lg * 4 + r;
      float bb = bias2[o];
      __bf16* dst = coef1 + ((size_t)n * CCH + o) * HW + px0;
#pragma unroll
      for (int j = 0; j < 4; ++j)
        dst[j * 16 + l15] = (__bf16)fmaxf(acc[i][j][r] + bb, 0.f);
    }
}

// ---------------------------------------------------------------------------
__global__ __launch_bounds__(256) void k_c2p(const __bf16* __restrict__ coef1,
                                             const float* __restrict__ w,
                                             float* __restrict__ part) {
  const int n = blockIdx.y;
  const int kc = blockIdx.z;
  const int p = blockIdx.x * 256 + threadIdx.x;
  const int px = p & 63, py = p >> 6;
  float acc[16];
#pragma unroll
  for (int o = 0; o < 16; ++o) acc[o] = 0.f;
  const __bf16* base = coef1 + (size_t)n * CCH * HW + (size_t)kc * 64 * HW;
  for (int c = 0; c < 64; ++c) {
    const __bf16* img = base + (size_t)c * HW;
    float v[9];
#pragma unroll
    for (int dy = -1; dy <= 1; ++dy)
#pragma unroll
      for (int dx = -1; dx <= 1; ++dx) {
        int yy = py + dy, xx = px + dx;
        bool ok = ((unsigned)yy < 64u) && ((unsigned)xx < 64u);
        v[(dy + 1) * 3 + dx + 1] = ok ? (float)img[yy * 64 + xx] : 0.f;
      }
    const int cg = kc * 64 + c;
#pragma unroll
    for (int o = 0; o < 16; ++o) {
      const float* wp = w + ((size_t)o * CCH + cg) * 9;
      float a = acc[o];
      a = fmaf(wp[0], v[0], a); a = fmaf(wp[1], v[1], a); a = fmaf(wp[2], v[2], a);
      a = fmaf(wp[3], v[3], a); a = fmaf(wp[4], v[4], a); a = fmaf(wp[5], v[5], a);
      a = fmaf(wp[6], v[6], a); a = fmaf(wp[7], v[7], a); a = fmaf(wp[8], v[8], a);
      acc[o] = a;
    }
  }
  float* dst = part + (((size_t)kc * 4 + n) * 16) * HW + p;
#pragma unroll
  for (int o = 0; o < 16; ++o) dst[(size_t)o * HW] = acc[o];
}

__global__ __launch_bounds__(256) void k_c2r(const float* __restrict__ part,
                                             const float* __restrict__ bias,
                                             float* __restrict__ c2o) {
  const int n = blockIdx.y;
  const int p = blockIdx.x * 256 + threadIdx.x;
#pragma unroll
  for (int o = 0; o < 16; ++o) {
    float s = bias[o];
#pragma unroll
    for (int kc = 0; kc < 4; ++kc)
      s += part[(((size_t)kc * 4 + n) * 16 + o) * HW + p];
    c2o[((size_t)n * 16 + o) * HW + p] = fmaxf(s, 0.f);
  }
}

// ---------------------------------------------------------------------------
__global__ __launch_bounds__(256) void k_c3(const float* __restrict__ c2o,
                                            const float* __restrict__ w,
                                            const float* __restrict__ bias,
                                            float* __restrict__ c3o) {
  const int n = blockIdx.y;
  const int p = blockIdx.x * 256 + threadIdx.x;
  const int px = p & 63, py = p >> 6;
  float acc[3] = {bias[0], bias[1], bias[2]};
  for (int c = 0; c < 16; ++c) {
    const float* img = c2o + ((size_t)n * 16 + c) * HW;
    float v[9];
#pragma unroll
    for (int dy = -1; dy <= 1; ++dy)
#pragma unroll
      for (int dx = -1; dx <= 1; ++dx) {
        int yy = py + dy, xx = px + dx;
        bool ok = ((unsigned)yy < 64u) && ((unsigned)xx < 64u);
        v[(dy + 1) * 3 + dx + 1] = ok ? img[yy * 64 + xx] : 0.f;
      }
#pragma unroll
    for (int o = 0; o < 3; ++o) {
      const float* wp = w + ((size_t)o * 16 + c) * 9;
      float a = acc[o];
      a = fmaf(wp[0], v[0], a); a = fmaf(wp[1], v[1], a); a = fmaf(wp[2], v[2], a);
      a = fmaf(wp[3], v[3], a); a = fmaf(wp[4], v[4], a); a = fmaf(wp[5], v[5], a);
      a = fmaf(wp[6], v[6], a); a = fmaf(wp[7], v[7], a); a = fmaf(wp[8], v[8], a);
      acc[o] = a;
    }
  }
#pragma unroll
  for (int o = 0; o < 3; ++o)
    c3o[((size_t)n * 3 + o) * HW + p] = fmaxf(acc[o], 0.f);
}

// ---------------------------------------------------------------------------
__global__ __launch_bounds__(256) void k_c4f(const float* __restrict__ c3o,
                                             const float* __restrict__ w4,
                                             const float* __restrict__ b4,
                                             const float* __restrict__ x,
                                             const __bf16* __restrict__ y2b,
                                             float* __restrict__ out0) {
  const int n = blockIdx.y;
  const int cc = blockIdx.z;
  const int p = blockIdx.x * 256 + threadIdx.x;
  const int px = p & 63, py = p >> 6;
  float coef = b4[0];
#pragma unroll
  for (int c = 0; c < 3; ++c) {
    const float* img = c3o + ((size_t)n * 3 + c) * HW;
#pragma unroll
    for (int dy = -1; dy <= 1; ++dy)
#pragma unroll
      for (int dx = -1; dx <= 1; ++dx) {
        int yy = py + dy, xx = px + dx;
        bool ok = ((unsigned)yy < 64u) && ((unsigned)xx < 64u);
        float v = ok ? img[yy * 64 + xx] : 0.f;
        coef = fmaf(w4[c * 9 + (dy + 1) * 3 + dx + 1], v, coef);
      }
  }
  const size_t base = ((size_t)n * CCH + cc * 64) * HW + p;
#pragma unroll 8
  for (int c = 0; c < 64; ++c) {
    size_t a = base + (size_t)c * HW;
    out0[a] = x[a] + coef * (float)y2b[a];
  }
}

// ---------------------------------------------------------------------------
extern "C" void kernel_launch(void* const* d_in, const int* in_sizes, int n_in,
                              void* d_out, int out_size, void* d_ws, size_t ws_size,
                              hipStream_t stream) {
  (void)in_sizes; (void)n_in; (void)out_size; (void)ws_size;
  const float* x     = (const float*)d_in[0];
  const float* x_ref = (const float*)d_in[1];
  const float* g_w   = (const float*)d_in[2];
  const float* g_b   = (const float*)d_in[3];
  const float* th_w  = (const float*)d_in[4];
  const float* th_b  = (const float*)d_in[5];
  const float* ph_w  = (const float*)d_in[6];
  const float* ph_b  = (const float*)d_in[7];
  const float* out_w = (const float*)d_in[8];
  const float* out_b = (const float*)d_in[9];
  const float* c1_w  = (const float*)d_in[10];
  const float* c1_b  = (const float*)d_in[11];
  const float* c2_w  = (const float*)d_in[12];
  const float* c2_b  = (const float*)d_in[13];
  const float* c3_w  = (const float*)d_in[14];
  const float* c3_b  = (const float*)d_in[15];
  const float* c4_w  = (const float*)d_in[16];
  const float* c4_b  = (const float*)d_in[17];

  float* ws = (float*)d_ws;
  __bf16* xB     = (__bf16*)(ws + 0);
  __bf16* yTB    = (__bf16*)(ws + 2097152);
  __bf16* thB    = (__bf16*)(ws + 3145728);
  __bf16* phB    = (__bf16*)(ws + 4194304);
  __bf16* gBf    = (__bf16*)(ws + 5242880);
  __bf16* coef1B = (__bf16*)(ws + 3145728);  // aliases thB+phB (dead after attn)
  __bf16* y2b    = (__bf16*)(ws + 6291456);
  float* c2p     = ws + 8388608;
  float* c2o     = ws + 9437184;
  float* c3o     = ws + 9699328;
  __bf16* c1xB   = (__bf16*)(ws + 9748480);
  __bf16* W2B    = (__bf16*)(ws + 9781248);
  __bf16* outwB  = (__bf16*)(ws + 9797632);
  float* bias2   = ws + 9814016;
  float* invW    = ws + 9814272;
  __bf16* Ews    = (__bf16*)(ws + 9830656);  // 67.1M bf16 = 134 MB

  float* out0 = (float*)d_out;
  float* P    = out0 + 4194304;

  dim3 blk(256);
  k_projT<<<dim3(64, 4), blk, 0, stream>>>(x, th_w, th_b, thB, xB);
  k_projPG<<<dim3(64, 4), blk, 0, stream>>>(x_ref, ph_w, g_w, ph_b, g_b, phB, gBf);
  k_prep<<<dim3(512), blk, 0, stream>>>(c1_w, c1_b, out_w, out_b, c1xB, W2B, outwB, bias2);
  k_attn2<<<dim3(64, 4), dim3(512), 0, stream>>>(thB, phB, gBf, outwB, out_b, Ews, invW, yTB, y2b);
  k_norm<<<dim3(64, 4), dim3(512), 0, stream>>>(Ews, invW, P);
  k_c1m<<<dim3(64, 4), blk, 0, stream>>>(xB, yTB, c1xB, W2B, bias2, coef1B);
  k_c2p<<<dim3(16, 4, 4), blk, 0, stream>>>(coef1B, c2_w, c2p);
  k_c2r<<<dim3(16, 4), blk, 0, stream>>>(c2p, c2_b, c2o);
  k_c3<<<dim3(16, 4), blk, 0, stream>>>(c2o, c3_w, c3_b, c3o);
  k_c4f<<<dim3(16, 4, 4), blk, 0, stream>>>(c3o, c4_w, c4_b, x, y2b, out0);
}